// Round 5
// baseline (1593.984 us; speedup 1.0000x reference)
//
#include <hip/hip_runtime.h>

// 2-layer LSTM (H=64) encode(128) + AR(60), B=4096, persistent per-block.
// 256 blocks x 1024 threads (16 waves = 4/SIMD). Two split axes:
//   grp   = wave layer group (0: layer1 / c1 / B1f; 1: layer0 / c0 / B0f,B0ar,Bfc)
//   whalf = accumulator-row half: GEMM duplicated (MFMA pipe has headroom),
//           epilogue split by rows r in {rbase, rbase+1} -> per-wave issue halves.
// -> 4 independent GEMM+epilogue chains per SIMD to hide trans/LDS/MFMA latency.
// Encode: 1 barrier/step. AR: 2 barriers/step with cross-phase MFMA pre-compute.
// x converted to fp16 LDS once -> no global loads in the main loop.

#define T_ENC 128
#define D_IN 4
#define H 64
#define STEPS 60
#define M 16
#define A0S 112   // halves/row: [x(4) | h0(64) | pad]; 56 dwords -> quad write groups on disjoint banks
#define A1S 144   // halves/row: [h0(64) | h1(64) | pad]; 72 dwords -> disjoint bank octets
#define XN (M * T_ENC * D_IN)   // 8192 halves
#define NT 1024

typedef _Float16 half8 __attribute__((ext_vector_type(8)));
typedef _Float16 half4_t __attribute__((ext_vector_type(4)));
typedef float float4v __attribute__((ext_vector_type(4)));

__device__ __forceinline__ float fast_sigmoid(float x) {
    float e = __builtin_amdgcn_exp2f(-1.44269504f * x);
    return __builtin_amdgcn_rcpf(1.0f + e);
}
__device__ __forceinline__ float fast_tanh(float x) {
    float e = __builtin_amdgcn_exp2f(2.88539008f * x);   // exp(2x)
    return __builtin_fmaf(-2.0f, __builtin_amdgcn_rcpf(e + 1.0f), 1.0f);
}

__global__ __launch_bounds__(NT, 4) void lstm_ar_kernel(
    const float* __restrict__ x,
    const float* __restrict__ Wih0, const float* __restrict__ Whh0,
    const float* __restrict__ bih0, const float* __restrict__ bhh0,
    const float* __restrict__ Wih1, const float* __restrict__ Whh1,
    const float* __restrict__ bih1, const float* __restrict__ bhh1,
    const float* __restrict__ Wfc,  const float* __restrict__ bfc,
    float* __restrict__ out)
{
    __shared__ __align__(16) _Float16 A0buf[2][M * A0S];
    __shared__ __align__(16) _Float16 A1buf[2][M * A1S];
    __shared__ __align__(16) _Float16 xAll[XN];                // [elem][t][d] fp16
    __shared__ __align__(16) float    predsS[M * STEPS * D_IN];

    const int tid   = threadIdx.x;
    const int wave  = tid >> 6;
    const int lane  = tid & 63;
    const int n16   = lane & 15;
    const int quad  = lane >> 4;
    const int w4    = wave & 3;          // hidden-column group
    const int grp   = (wave >> 2) & 1;   // 0: layer-1, 1: layer-0
    const int whalf = wave >> 3;         // accumulator-row half
    const int rbase = whalf * 2;
    const int m0    = blockIdx.x * M;
    const int m     = n16;               // A-frag row (batch element)
    const int jcol  = 16 * w4 + n16;     // hidden column owned in epilogues

    { _Float16* z = &A0buf[0][0]; for (int i = tid; i < 2 * M * A0S; i += NT) z[i] = (_Float16)0.f; }
    { _Float16* z = &A1buf[0][0]; for (int i = tid; i < 2 * M * A1S; i += NT) z[i] = (_Float16)0.f; }
    // x -> fp16 LDS (one-time; removes all global loads from the main loop)
    for (int j = tid; j < XN / 4; j += NT) {
        const float4v v = *(const float4v*)&x[(size_t)m0 * T_ENC * D_IN + (size_t)j * 4];
        *(half4_t*)&xAll[j * 4] =
            (half4_t){(_Float16)v[0], (_Float16)v[1], (_Float16)v[2], (_Float16)v[3]};
    }

    // ---- per-group weight fragments: B[k][n], n = 16*(w4 + 4*tau) + n16, tau = gate ----
    half8 B1f[4][4];             // grp0: layer1, K=128 = [h0 | h1]
    half8 B0f[3][4];             // grp1: encode layer0, K=96 = [x(4); h0(64); pad]
    float b1v[4], b0v[4], b0arv[4];
    if (grp == 0) {
        #pragma unroll
        for (int tau = 0; tau < 4; ++tau) {
            const int n = 16 * (w4 + 4 * tau) + n16;
            b1v[tau] = bih1[n] + bhh1[n];
            #pragma unroll
            for (int kt = 0; kt < 4; ++kt)
                #pragma unroll
                for (int j = 0; j < 8; ++j) {
                    const int k = kt * 32 + quad * 8 + j;
                    B1f[kt][tau][j] = (_Float16)((k < H) ? Wih1[n * H + k] : Whh1[n * H + (k - H)]);
                }
        }
    } else {
        #pragma unroll
        for (int tau = 0; tau < 4; ++tau) {
            const int n = 16 * (w4 + 4 * tau) + n16;
            b0v[tau] = bih0[n] + bhh0[n];
            float wb = 0.f;
            #pragma unroll
            for (int d = 0; d < 4; ++d) wb += Wih0[n * D_IN + d] * bfc[d];
            b0arv[tau] = b0v[tau] + wb;
            #pragma unroll
            for (int kt = 0; kt < 3; ++kt)
                #pragma unroll
                for (int j = 0; j < 8; ++j) {
                    const int k = kt * 32 + quad * 8 + j;
                    float v = 0.f;
                    if (k < 4)       v = Wih0[n * D_IN + k];
                    else if (k < 68) v = Whh0[n * H + (k - 4)];
                    B0f[kt][tau][j] = (_Float16)v;
                }
        }
    }

    float c0s[2] = {0.f, 0.f};   // grp1 state (rows rbase..rbase+1)
    float c1s[2] = {0.f, 0.f};   // grp0 state

    __syncthreads();   // LDS zero + xAll ready

    // x(0) -> A0buf[1] x-slot (prologue input); x(1) -> A0buf[0] (iter-0 input)
    if (grp == 1 && w4 == 2 && whalf == 0 && lane < 16) {
        *(half4_t*)&A0buf[1][lane * A0S] = *(const half4_t*)&xAll[(lane * T_ENC + 0) * D_IN];
        *(half4_t*)&A0buf[0][lane * A0S] = *(const half4_t*)&xAll[(lane * T_ENC + 1) * D_IN];
    }
    __syncthreads();

    // ---- prologue: L0 step 0 (grp1, both whalf duplicate GEMM, split epilogue) ----
    if (grp == 1) {
        half8 a0f[3];
        #pragma unroll
        for (int kt = 0; kt < 3; ++kt)
            a0f[kt] = *(const half8*)&A0buf[1][m * A0S + kt * 32 + quad * 8];
        float4v C0[4];
        #pragma unroll
        for (int tau = 0; tau < 4; ++tau)
            C0[tau] = (float4v){b0v[tau], b0v[tau], b0v[tau], b0v[tau]};
        #pragma unroll
        for (int kt = 0; kt < 3; ++kt)
            #pragma unroll
            for (int tau = 0; tau < 4; ++tau)
                C0[tau] = __builtin_amdgcn_mfma_f32_16x16x32_f16(a0f[kt], B0f[kt][tau], C0[tau], 0, 0, 0);
        #pragma unroll
        for (int rr = 0; rr < 2; ++rr) {
            const int r = rbase + rr;
            const float ig = fast_sigmoid(C0[0][r]);
            const float fg = fast_sigmoid(C0[1][r]);
            const float gg = fast_tanh   (C0[2][r]);
            const float og = fast_sigmoid(C0[3][r]);
            const float c  = fg * c0s[rr] + ig * gg;
            c0s[rr] = c;
            const _Float16 hh = (_Float16)(og * fast_tanh(c));
            const int row = quad * 4 + r;
            A1buf[0][row * A1S + jcol]     = hh;
            A0buf[0][row * A0S + 4 + jcol] = hh;
        }
    }
    __syncthreads();

    // ---- encode: iter t = L1(t) on grp0  ||  L0(t+1) on grp1; 1 barrier ----
    for (int t = 0; t < T_ENC; ++t) {
        const int p = t & 1;
        if (grp == 0) {
            const _Float16* cur1 = &A1buf[p][0];
            _Float16* nxt1 = &A1buf[1 - p][0];
            half8 a1f[4];
            #pragma unroll
            for (int kt = 0; kt < 4; ++kt)
                a1f[kt] = *(const half8*)&cur1[m * A1S + kt * 32 + quad * 8];
            float4v C1[4];
            #pragma unroll
            for (int tau = 0; tau < 4; ++tau)
                C1[tau] = (float4v){b1v[tau], b1v[tau], b1v[tau], b1v[tau]};
            #pragma unroll
            for (int kt = 0; kt < 4; ++kt)
                #pragma unroll
                for (int tau = 0; tau < 4; ++tau)
                    C1[tau] = __builtin_amdgcn_mfma_f32_16x16x32_f16(a1f[kt], B1f[kt][tau], C1[tau], 0, 0, 0);
            #pragma unroll
            for (int rr = 0; rr < 2; ++rr) {
                const int r = rbase + rr;
                const float ig = fast_sigmoid(C1[0][r]);
                const float fg = fast_sigmoid(C1[1][r]);
                const float gg = fast_tanh   (C1[2][r]);
                const float og = fast_sigmoid(C1[3][r]);
                const float c  = fg * c1s[rr] + ig * gg;
                c1s[rr] = c;
                nxt1[(quad * 4 + r) * A1S + 64 + jcol] = (_Float16)(og * fast_tanh(c));
            }
        } else {
            const _Float16* cur0 = &A0buf[p][0];
            _Float16* nxt0 = &A0buf[1 - p][0];
            _Float16* nxt1 = &A1buf[1 - p][0];
            half8 a0f[3];
            #pragma unroll
            for (int kt = 0; kt < 3; ++kt)
                a0f[kt] = *(const half8*)&cur0[m * A0S + kt * 32 + quad * 8];
            float4v C0[4];
            #pragma unroll
            for (int tau = 0; tau < 4; ++tau)
                C0[tau] = (float4v){b0v[tau], b0v[tau], b0v[tau], b0v[tau]};
            #pragma unroll
            for (int kt = 0; kt < 3; ++kt)
                #pragma unroll
                for (int tau = 0; tau < 4; ++tau)
                    C0[tau] = __builtin_amdgcn_mfma_f32_16x16x32_f16(a0f[kt], B0f[kt][tau], C0[tau], 0, 0, 0);
            #pragma unroll
            for (int rr = 0; rr < 2; ++rr) {
                const int r = rbase + rr;
                const float ig = fast_sigmoid(C0[0][r]);
                const float fg = fast_sigmoid(C0[1][r]);
                const float gg = fast_tanh   (C0[2][r]);
                const float og = fast_sigmoid(C0[3][r]);
                const float c  = fg * c0s[rr] + ig * gg;
                c0s[rr] = c;
                const _Float16 hh = (_Float16)(og * fast_tanh(c));
                const int row = quad * 4 + r;
                nxt1[row * A1S + jcol]     = hh;
                nxt0[row * A0S + 4 + jcol] = hh;
            }
            if (w4 == 2 && whalf == 0 && lane < 16) {   // x(t+2) -> nxt0 x-slot
                int tn = t + 2; if (tn > T_ENC - 1) tn = T_ENC - 1;
                *(half4_t*)&nxt0[lane * A0S] = *(const half4_t*)&xAll[(lane * T_ENC + tn) * D_IN];
            }
        }
        __syncthreads();
    }

    // ---- AR weights: grp1 swaps B0f -> B0ar = [Whh0 | Wih0@Wfc], Bfc on w4==0 ----
    half8 B0ar[4][4];
    half8 Bfc[2];
    float bfcv = 0.f;
    if (grp == 1) {
        #pragma unroll
        for (int tau = 0; tau < 4; ++tau) {
            const int n = 16 * (w4 + 4 * tau) + n16;
            #pragma unroll
            for (int kt = 0; kt < 4; ++kt)
                #pragma unroll
                for (int j = 0; j < 8; ++j) {
                    const int k = kt * 32 + quad * 8 + j;
                    float v;
                    if (k < H) v = Whh0[n * H + k];
                    else {
                        const int c = k - H;
                        v = Wih0[n * D_IN + 0] * Wfc[0 * H + c] + Wih0[n * D_IN + 1] * Wfc[1 * H + c]
                          + Wih0[n * D_IN + 2] * Wfc[2 * H + c] + Wih0[n * D_IN + 3] * Wfc[3 * H + c];
                    }
                    B0ar[kt][tau][j] = (_Float16)v;
                }
        }
        if (w4 == 0) {
            #pragma unroll
            for (int kt = 0; kt < 2; ++kt)
                #pragma unroll
                for (int j = 0; j < 8; ++j) {
                    const int k = kt * 32 + quad * 8 + j;
                    Bfc[kt][j] = (_Float16)((n16 < 4) ? Wfc[n16 * H + k] : 0.f);
                }
            if (n16 < 4) bfcv = bfc[n16];
        }
    }
    // grp0 overlaps: C1pre(0) = b1 + Whh1 · h1(127)
    float4v C1pre[4];
    if (grp == 0) {
        half8 ah[2];
        #pragma unroll
        for (int kt = 0; kt < 2; ++kt)
            ah[kt] = *(const half8*)&A1buf[0][m * A1S + 64 + kt * 32 + quad * 8];
        #pragma unroll
        for (int tau = 0; tau < 4; ++tau)
            C1pre[tau] = (float4v){b1v[tau], b1v[tau], b1v[tau], b1v[tau]};
        #pragma unroll
        for (int kt = 0; kt < 2; ++kt)
            #pragma unroll
            for (int tau = 0; tau < 4; ++tau)
                C1pre[tau] = __builtin_amdgcn_mfma_f32_16x16x32_f16(ah[kt], B1f[2 + kt][tau], C1pre[tau], 0, 0, 0);
    }

    // ---- AR: phase1 = L1 finish (grp0) || Whh0-pre (grp1); B1;
    //          phase2 = L0ar finish + head (grp1) || Whh1-pre (grp0); B2 ----
    for (int s = 0; s < STEPS; ++s) {
        const int q = s & 1;
        const _Float16* cur = &A1buf[q][0];
        _Float16* nxt = &A1buf[1 - q][0];

        half8 ah0[2];   // h0(s)
        #pragma unroll
        for (int kt = 0; kt < 2; ++kt)
            ah0[kt] = *(const half8*)&cur[m * A1S + kt * 32 + quad * 8];

        float4v C0pre[4];
        if (grp == 0) {
            float4v C1[4] = {C1pre[0], C1pre[1], C1pre[2], C1pre[3]};
            #pragma unroll
            for (int kt = 0; kt < 2; ++kt)
                #pragma unroll
                for (int tau = 0; tau < 4; ++tau)
                    C1[tau] = __builtin_amdgcn_mfma_f32_16x16x32_f16(ah0[kt], B1f[kt][tau], C1[tau], 0, 0, 0);
            #pragma unroll
            for (int rr = 0; rr < 2; ++rr) {
                const int r = rbase + rr;
                const float ig = fast_sigmoid(C1[0][r]);
                const float fg = fast_sigmoid(C1[1][r]);
                const float gg = fast_tanh   (C1[2][r]);
                const float og = fast_sigmoid(C1[3][r]);
                const float c  = fg * c1s[rr] + ig * gg;
                c1s[rr] = c;
                nxt[(quad * 4 + r) * A1S + 64 + jcol] = (_Float16)(og * fast_tanh(c));
            }
        } else {
            #pragma unroll
            for (int tau = 0; tau < 4; ++tau)
                C0pre[tau] = (float4v){b0arv[tau], b0arv[tau], b0arv[tau], b0arv[tau]};
            #pragma unroll
            for (int kt = 0; kt < 2; ++kt)
                #pragma unroll
                for (int tau = 0; tau < 4; ++tau)
                    C0pre[tau] = __builtin_amdgcn_mfma_f32_16x16x32_f16(ah0[kt], B0ar[kt][tau], C0pre[tau], 0, 0, 0);
        }
        __syncthreads();   // B1: h1(s) visible

        half8 ah1[2];   // h1(s)
        #pragma unroll
        for (int kt = 0; kt < 2; ++kt)
            ah1[kt] = *(const half8*)&nxt[m * A1S + 64 + kt * 32 + quad * 8];

        if (grp == 1) {
            float4v C0[4] = {C0pre[0], C0pre[1], C0pre[2], C0pre[3]};
            #pragma unroll
            for (int kt = 0; kt < 2; ++kt)
                #pragma unroll
                for (int tau = 0; tau < 4; ++tau)
                    C0[tau] = __builtin_amdgcn_mfma_f32_16x16x32_f16(ah1[kt], B0ar[2 + kt][tau], C0[tau], 0, 0, 0);
            if (w4 == 0) {   // head: pred(s) = Wfc·h1(s)+bfc, off critical path; each whalf writes its rows
                float4v Cp = (float4v){bfcv, bfcv, bfcv, bfcv};
                Cp = __builtin_amdgcn_mfma_f32_16x16x32_f16(ah1[0], Bfc[0], Cp, 0, 0, 0);
                Cp = __builtin_amdgcn_mfma_f32_16x16x32_f16(ah1[1], Bfc[1], Cp, 0, 0, 0);
                if (n16 < 4) {
                    #pragma unroll
                    for (int rr = 0; rr < 2; ++rr) {
                        const int r = rbase + rr;
                        predsS[(quad * 4 + r) * (STEPS * D_IN) + s * D_IN + n16] = Cp[r];
                    }
                }
            }
            #pragma unroll
            for (int rr = 0; rr < 2; ++rr) {
                const int r = rbase + rr;
                const float ig = fast_sigmoid(C0[0][r]);
                const float fg = fast_sigmoid(C0[1][r]);
                const float gg = fast_tanh   (C0[2][r]);
                const float og = fast_sigmoid(C0[3][r]);
                const float c  = fg * c0s[rr] + ig * gg;
                c0s[rr] = c;
                nxt[(quad * 4 + r) * A1S + jcol] = (_Float16)(og * fast_tanh(c));
            }
        } else {   // grp0 pre-computes C1pre(s+1) = b1 + Whh1·h1(s)
            #pragma unroll
            for (int tau = 0; tau < 4; ++tau)
                C1pre[tau] = (float4v){b1v[tau], b1v[tau], b1v[tau], b1v[tau]};
            #pragma unroll
            for (int kt = 0; kt < 2; ++kt)
                #pragma unroll
                for (int tau = 0; tau < 4; ++tau)
                    C1pre[tau] = __builtin_amdgcn_mfma_f32_16x16x32_f16(ah1[kt], B1f[2 + kt][tau], C1pre[tau], 0, 0, 0);
        }
        __syncthreads();   // B2: h0(s+1) visible
    }

    // ---- bulk store preds ----
    for (int j = tid; j < M * STEPS; j += NT) {
        const int elem = j / STEPS, r = j - elem * STEPS;
        ((float4v*)out)[(size_t)(m0 + elem) * STEPS + r] = ((const float4v*)predsS)[j];
    }
}

extern "C" void kernel_launch(void* const* d_in, const int* in_sizes, int n_in,
                              void* d_out, int out_size, void* d_ws, size_t ws_size,
                              hipStream_t stream) {
    const float* x    = (const float*)d_in[0];
    const float* Wih0 = (const float*)d_in[1];
    const float* Whh0 = (const float*)d_in[2];
    const float* bih0 = (const float*)d_in[3];
    const float* bhh0 = (const float*)d_in[4];
    const float* Wih1 = (const float*)d_in[5];
    const float* Whh1 = (const float*)d_in[6];
    const float* bih1 = (const float*)d_in[7];
    const float* bhh1 = (const float*)d_in[8];
    const float* Wfc  = (const float*)d_in[9];
    const float* bfc  = (const float*)d_in[10];
    float* out = (float*)d_out;

    dim3 grid(4096 / M);   // 256 blocks, one per CU
    dim3 block(NT);        // 16 waves = 4 per SIMD (grp x whalf x colgroup)
    lstm_ar_kernel<<<grid, block, 0, stream>>>(
        x, Wih0, Whh0, bih0, bhh0, Wih1, Whh1, bih1, bhh1, Wfc, bfc, out);
}

// Round 6
// 870.967 us; speedup vs baseline: 1.8301x; 1.8301x over previous
//
#include <hip/hip_runtime.h>

// 2-layer LSTM (H=64) encode(128) + AR(60), B=4096, persistent per-block.
// 256 blocks x 1024 threads (16 waves = 4/SIMD). Wave = (w4, grp, whalf):
//   grp0 owns layer1 (c1), grp1 owns layer0 (c0); whalf pair duplicates the
//   GEMM (MFMA has headroom) and splits the epilogue rows -> 20 trans/wave.
// Register diet (R5 spilled at ~200 regs under the 128 cap):
//   - ONE BW[4][4] weight array, contents per-group; grp1 overwrites in place
//     at AR start with [Whh0 | Wih0@Wfc] (pred folded off the critical path).
//   - ONE merged LDS state buffer/parity: row=[x(4)|pad|h0(64)|h1(64)|pad].
//   - ONE Cacc accumulator, reused as the AR cross-phase carry.
//   - Head Wfc fragment lives in LDS, re-read per step (2 ds_reads, 0 regs).

#define T_ENC 128
#define D_IN 4
#define H 64
#define STEPS 60
#define M 16
#define S 152      // halves per state row (76 dwords; quad write-groups 2-way max)
#define H0OFF 8
#define H1OFF 72
#define NT 1024
#define XN (M * T_ENC * D_IN)   // 8192 halves

typedef _Float16 half8 __attribute__((ext_vector_type(8)));
typedef _Float16 half4_t __attribute__((ext_vector_type(4)));
typedef float float4v __attribute__((ext_vector_type(4)));

__device__ __forceinline__ float fast_sigmoid(float x) {
    float e = __builtin_amdgcn_exp2f(-1.44269504f * x);
    return __builtin_amdgcn_rcpf(1.0f + e);
}
__device__ __forceinline__ float fast_tanh(float x) {
    float e = __builtin_amdgcn_exp2f(2.88539008f * x);   // exp(2x)
    return __builtin_fmaf(-2.0f, __builtin_amdgcn_rcpf(e + 1.0f), 1.0f);
}

__global__ __launch_bounds__(NT, 4) void lstm_ar_kernel(
    const float* __restrict__ x,
    const float* __restrict__ Wih0, const float* __restrict__ Whh0,
    const float* __restrict__ bih0, const float* __restrict__ bhh0,
    const float* __restrict__ Wih1, const float* __restrict__ Whh1,
    const float* __restrict__ bih1, const float* __restrict__ bhh1,
    const float* __restrict__ Wfc,  const float* __restrict__ bfc,
    float* __restrict__ out)
{
    __shared__ __align__(16) _Float16 buf[2][M * S];
    __shared__ __align__(16) _Float16 xAll[XN];            // [elem][t][d] fp16
    __shared__ __align__(16) _Float16 BfcL[16 * 64];       // Wfc in B-frag order
    __shared__ __align__(16) float    predsS[M * STEPS * D_IN];

    const int tid   = threadIdx.x;
    const int wave  = tid >> 6;
    const int lane  = tid & 63;
    const int n16   = lane & 15;
    const int quad  = lane >> 4;
    const int w4    = wave & 3;
    const int grp   = (wave >> 2) & 1;   // 0: layer1, 1: layer0
    const int whalf = wave >> 3;
    const int rbase = whalf * 2;
    const int m0    = blockIdx.x * M;
    const int m     = n16;
    const int jcol  = 16 * w4 + n16;

    { _Float16* z = &buf[0][0]; for (int i = tid; i < 2 * M * S; i += NT) z[i] = (_Float16)0.f; }
    for (int j = tid; j < XN / 4; j += NT) {
        const float4v v = *(const float4v*)&x[(size_t)m0 * T_ENC * D_IN + (size_t)j * 4];
        *(half4_t*)&xAll[j * 4] =
            (half4_t){(_Float16)v[0], (_Float16)v[1], (_Float16)v[2], (_Float16)v[3]};
    }
    {   // Wfc -> B-frag layout: BfcL[n*64 + k] = n<4 ? Wfc[n][k] : 0
        const int n = tid >> 6, k = tid & 63;
        BfcL[tid] = (_Float16)((n < 4) ? Wfc[n * H + k] : 0.f);
    }

    // ---- weights: ONE BW array, per-group contents ----
    half8 BW[4][4];
    float bias[4];
    #pragma unroll
    for (int tau = 0; tau < 4; ++tau) {
        const int n = 16 * (w4 + 4 * tau) + n16;
        if (grp == 0) {
            bias[tau] = bih1[n] + bhh1[n];
            #pragma unroll
            for (int kt = 0; kt < 4; ++kt)
                #pragma unroll
                for (int j = 0; j < 8; ++j) {
                    const int k = kt * 32 + quad * 8 + j;
                    BW[kt][tau][j] = (_Float16)((k < H) ? Wih1[n * H + k] : Whh1[n * H + (k - H)]);
                }
        } else {
            bias[tau] = bih0[n] + bhh0[n];
            #pragma unroll
            for (int kt = 0; kt < 4; ++kt)
                #pragma unroll
                for (int j = 0; j < 8; ++j) {
                    const int k = kt * 32 + quad * 8 + j;
                    float v = 0.f;
                    if (k < 4)                     v = Wih0[n * D_IN + k];
                    else if (k >= H0OFF && k < H0OFF + H) v = Whh0[n * H + (k - H0OFF)];
                    BW[kt][tau][j] = (_Float16)v;   // zero for k in [4,8) and [72,96); kt=3 all zero
                }
        }
    }

    float cst[2] = {0.f, 0.f};
    float4v Cacc[4];
    half8 af[4];

    __syncthreads();   // zero + xAll + BfcL done

    if (grp == 1 && w4 == 2 && whalf == 0 && lane < 16) {
        *(half4_t*)&buf[1][lane * S] = *(const half4_t*)&xAll[(lane * T_ENC + 0) * D_IN];
        *(half4_t*)&buf[0][lane * S] = *(const half4_t*)&xAll[(lane * T_ENC + 1) * D_IN];
    }
    __syncthreads();

    // ---- prologue: L0(0) on grp1 (dup GEMM, split epilogue) ----
    if (grp == 1) {
        #pragma unroll
        for (int kt = 0; kt < 3; ++kt)
            af[kt] = *(const half8*)&buf[1][m * S + kt * 32 + quad * 8];
        #pragma unroll
        for (int tau = 0; tau < 4; ++tau)
            Cacc[tau] = (float4v){bias[tau], bias[tau], bias[tau], bias[tau]};
        #pragma unroll
        for (int kt = 0; kt < 3; ++kt)
            #pragma unroll
            for (int tau = 0; tau < 4; ++tau)
                Cacc[tau] = __builtin_amdgcn_mfma_f32_16x16x32_f16(af[kt], BW[kt][tau], Cacc[tau], 0, 0, 0);
        #pragma unroll
        for (int rr = 0; rr < 2; ++rr) {
            const int r = rbase + rr;
            const float ig = fast_sigmoid(Cacc[0][r]);
            const float fg = fast_sigmoid(Cacc[1][r]);
            const float gg = fast_tanh   (Cacc[2][r]);
            const float og = fast_sigmoid(Cacc[3][r]);
            const float c  = fg * cst[rr] + ig * gg;
            cst[rr] = c;
            buf[0][(quad * 4 + r) * S + H0OFF + jcol] = (_Float16)(og * fast_tanh(c));
        }
    }
    __syncthreads();

    // ---- encode: interval t = L1(t) on grp0 || L0(t+1) on grp1; 1 barrier ----
    for (int t = 0; t < T_ENC; ++t) {
        const int p = t & 1;
        const _Float16* cur = &buf[p][0];
        _Float16* nxt = &buf[1 - p][0];
        const int aoff = grp ? 0 : H0OFF;
        const int nkt  = grp ? 3 : 4;
        #pragma unroll
        for (int kt = 0; kt < 4; ++kt)
            if (kt < nkt)
                af[kt] = *(const half8*)&cur[m * S + aoff + kt * 32 + quad * 8];
        #pragma unroll
        for (int tau = 0; tau < 4; ++tau)
            Cacc[tau] = (float4v){bias[tau], bias[tau], bias[tau], bias[tau]};
        #pragma unroll
        for (int kt = 0; kt < 4; ++kt)
            if (kt < nkt)
                #pragma unroll
                for (int tau = 0; tau < 4; ++tau)
                    Cacc[tau] = __builtin_amdgcn_mfma_f32_16x16x32_f16(af[kt], BW[kt][tau], Cacc[tau], 0, 0, 0);
        const int hoff = grp ? H0OFF : H1OFF;
        #pragma unroll
        for (int rr = 0; rr < 2; ++rr) {
            const int r = rbase + rr;
            const float ig = fast_sigmoid(Cacc[0][r]);
            const float fg = fast_sigmoid(Cacc[1][r]);
            const float gg = fast_tanh   (Cacc[2][r]);
            const float og = fast_sigmoid(Cacc[3][r]);
            const float c  = fg * cst[rr] + ig * gg;
            cst[rr] = c;
            nxt[(quad * 4 + r) * S + hoff + jcol] = (_Float16)(og * fast_tanh(c));
        }
        if (grp == 1 && w4 == 2 && whalf == 0 && lane < 16) {
            int tn = t + 2; if (tn > T_ENC - 1) tn = T_ENC - 1;
            *(half4_t*)&nxt[lane * S] = *(const half4_t*)&xAll[(lane * T_ENC + tn) * D_IN];
        }
        __syncthreads();
    }

    // ---- AR prep: grp1 overwrites BW in place -> [Whh0 | Wx=Wih0@Wfc], bias += Wih0·bfc ----
    if (grp == 1) {
        #pragma unroll
        for (int tau = 0; tau < 4; ++tau) {
            const int n = 16 * (w4 + 4 * tau) + n16;
            float wb = 0.f;
            #pragma unroll
            for (int d = 0; d < 4; ++d) wb += Wih0[n * D_IN + d] * bfc[d];
            bias[tau] += wb;
            #pragma unroll
            for (int kt = 0; kt < 4; ++kt)
                #pragma unroll
                for (int j = 0; j < 8; ++j) {
                    const int k = kt * 32 + quad * 8 + j;
                    float v;
                    if (k < H) v = Whh0[n * H + k];
                    else {
                        const int c = k - H;
                        v = Wih0[n * D_IN + 0] * Wfc[0 * H + c] + Wih0[n * D_IN + 1] * Wfc[1 * H + c]
                          + Wih0[n * D_IN + 2] * Wfc[2 * H + c] + Wih0[n * D_IN + 3] * Wfc[3 * H + c];
                    }
                    BW[kt][tau][j] = (_Float16)v;
                }
        }
    } else {
        // Cacc := bias + Whh1·h1(127)  (carry into AR phase1 of s=0)
        #pragma unroll
        for (int kt = 0; kt < 2; ++kt)
            af[kt] = *(const half8*)&buf[0][m * S + H1OFF + kt * 32 + quad * 8];
        #pragma unroll
        for (int tau = 0; tau < 4; ++tau)
            Cacc[tau] = (float4v){bias[tau], bias[tau], bias[tau], bias[tau]};
        #pragma unroll
        for (int kt = 0; kt < 2; ++kt)
            #pragma unroll
            for (int tau = 0; tau < 4; ++tau)
                Cacc[tau] = __builtin_amdgcn_mfma_f32_16x16x32_f16(af[kt], BW[2 + kt][tau], Cacc[tau], 0, 0, 0);
    }
    const float bfcv = (grp == 0 && w4 == 0 && n16 < 4) ? bfc[n16] : 0.f;

    // ---- AR: phase1 = h1(s) finish (grp0) || Whh0·h0(s) pre (grp1); barrier;
    //          phase2 = h0(s+1) finish + head (grp1/grp0-w4==0) || Whh1·h1(s) pre (grp0); barrier ----
    for (int s = 0; s < STEPS; ++s) {
        const int q = s & 1;
        const _Float16* cur = &buf[q][0];
        _Float16* nxt = &buf[1 - q][0];

        #pragma unroll
        for (int kt = 0; kt < 2; ++kt)
            af[kt] = *(const half8*)&cur[m * S + H0OFF + kt * 32 + quad * 8];   // h0(s)
        if (grp == 1) {
            #pragma unroll
            for (int tau = 0; tau < 4; ++tau)
                Cacc[tau] = (float4v){bias[tau], bias[tau], bias[tau], bias[tau]};
        }
        #pragma unroll
        for (int kt = 0; kt < 2; ++kt)
            #pragma unroll
            for (int tau = 0; tau < 4; ++tau)
                Cacc[tau] = __builtin_amdgcn_mfma_f32_16x16x32_f16(af[kt], BW[grp ? kt : kt][tau], Cacc[tau], 0, 0, 0);
        if (grp == 0) {   // finish gates1(s) -> h1(s)
            #pragma unroll
            for (int rr = 0; rr < 2; ++rr) {
                const int r = rbase + rr;
                const float ig = fast_sigmoid(Cacc[0][r]);
                const float fg = fast_sigmoid(Cacc[1][r]);
                const float gg = fast_tanh   (Cacc[2][r]);
                const float og = fast_sigmoid(Cacc[3][r]);
                const float c  = fg * cst[rr] + ig * gg;
                cst[rr] = c;
                nxt[(quad * 4 + r) * S + H1OFF + jcol] = (_Float16)(og * fast_tanh(c));
            }
        }
        __syncthreads();   // h1(s) visible

        #pragma unroll
        for (int kt = 0; kt < 2; ++kt)
            af[kt] = *(const half8*)&nxt[m * S + H1OFF + kt * 32 + quad * 8];   // h1(s)
        if (grp == 1) {   // finish gates0(s+1) -> h0(s+1)
            #pragma unroll
            for (int kt = 0; kt < 2; ++kt)
                #pragma unroll
                for (int tau = 0; tau < 4; ++tau)
                    Cacc[tau] = __builtin_amdgcn_mfma_f32_16x16x32_f16(af[kt], BW[2 + kt][tau], Cacc[tau], 0, 0, 0);
            #pragma unroll
            for (int rr = 0; rr < 2; ++rr) {
                const int r = rbase + rr;
                const float ig = fast_sigmoid(Cacc[0][r]);
                const float fg = fast_sigmoid(Cacc[1][r]);
                const float gg = fast_tanh   (Cacc[2][r]);
                const float og = fast_sigmoid(Cacc[3][r]);
                const float c  = fg * cst[rr] + ig * gg;
                cst[rr] = c;
                nxt[(quad * 4 + r) * S + H0OFF + jcol] = (_Float16)(og * fast_tanh(c));
            }
        } else {
            if (w4 == 0) {   // head: pred(s) = Wfc·h1(s)+bfc (off critical path)
                float4v Cp = (float4v){bfcv, bfcv, bfcv, bfcv};
                #pragma unroll
                for (int kt = 0; kt < 2; ++kt) {
                    const half8 bf = *(const half8*)&BfcL[n16 * H + kt * 32 + quad * 8];
                    Cp = __builtin_amdgcn_mfma_f32_16x16x32_f16(af[kt], bf, Cp, 0, 0, 0);
                }
                if (n16 < 4) {
                    #pragma unroll
                    for (int rr = 0; rr < 2; ++rr) {
                        const int r = rbase + rr;
                        predsS[(quad * 4 + r) * (STEPS * D_IN) + s * D_IN + n16] = Cp[r];
                    }
                }
            }
            // Cacc := bias + Whh1·h1(s)  (carry to next phase1)
            #pragma unroll
            for (int tau = 0; tau < 4; ++tau)
                Cacc[tau] = (float4v){bias[tau], bias[tau], bias[tau], bias[tau]};
            #pragma unroll
            for (int kt = 0; kt < 2; ++kt)
                #pragma unroll
                for (int tau = 0; tau < 4; ++tau)
                    Cacc[tau] = __builtin_amdgcn_mfma_f32_16x16x32_f16(af[kt], BW[2 + kt][tau], Cacc[tau], 0, 0, 0);
        }
        __syncthreads();   // h0(s+1) visible
    }

    // ---- bulk store preds ----
    for (int j = tid; j < M * STEPS; j += NT) {
        const int elem = j / STEPS, r = j - elem * STEPS;
        ((float4v*)out)[(size_t)(m0 + elem) * STEPS + r] = ((const float4v*)predsS)[j];
    }
}

extern "C" void kernel_launch(void* const* d_in, const int* in_sizes, int n_in,
                              void* d_out, int out_size, void* d_ws, size_t ws_size,
                              hipStream_t stream) {
    const float* x    = (const float*)d_in[0];
    const float* Wih0 = (const float*)d_in[1];
    const float* Whh0 = (const float*)d_in[2];
    const float* bih0 = (const float*)d_in[3];
    const float* bhh0 = (const float*)d_in[4];
    const float* Wih1 = (const float*)d_in[5];
    const float* Whh1 = (const float*)d_in[6];
    const float* bih1 = (const float*)d_in[7];
    const float* bhh1 = (const float*)d_in[8];
    const float* Wfc  = (const float*)d_in[9];
    const float* bfc  = (const float*)d_in[10];
    float* out = (float*)d_out;

    dim3 grid(4096 / M);   // 256 blocks, one per CU
    dim3 block(NT);        // 16 waves = 4 per SIMD
    lstm_ar_kernel<<<grid, block, 0, stream>>>(
        x, Wih0, Whh0, bih0, bhh0, Wih1, Whh1, bih1, bhh1, Wfc, bfc, out);
}

// Round 7
// 326.911 us; speedup vs baseline: 4.8759x; 2.6642x over previous
//
#include <hip/hip_runtime.h>

// 2-layer LSTM (H=64) encode(128) + AR(60), B=4096, persistent per-block.
// 256 blocks x 512 threads (8 waves = 2/SIMD). Every wave runs the retimed
// both-layer body (L1(t) and L0(t+1) are independent -> 2 ILP chains/wave);
// whalf = wave>>2 duplicates the GEMMs (MFMA pipe has headroom) and splits
// the epilogue accumulator rows 2+2 -> per-wave trans issue halves, giving
// 4 independent GEMM->epilogue chains per SIMD.
// 1 barrier per encode step; 2 per AR step (pred folded via Wx = Wih0@Wfc,
// so the pred->x round-trip is off the critical path). x lives in LDS (fp16).
// NOTE: 1024-thread variants spill to scratch (R5/R6: VGPR capped at 64,
// GB-scale FETCH). Stay in the 512-thread / 256-VGPR envelope.

#define T_ENC 128
#define D_IN 4
#define H 64
#define STEPS 60
#define M 16
#define A0S 104   // halves/row: [x(4) | h0(64) | zero-pad]
#define A1S 136   // halves/row: [h0(64) | h1(64)] + slack
#define XN (M * T_ENC * D_IN)   // 8192 halves
#define NT 512

typedef _Float16 half8 __attribute__((ext_vector_type(8)));
typedef _Float16 half4_t __attribute__((ext_vector_type(4)));
typedef float float4v __attribute__((ext_vector_type(4)));

__device__ __forceinline__ float fast_sigmoid(float x) {
    float e = __builtin_amdgcn_exp2f(-1.44269504f * x);
    return __builtin_amdgcn_rcpf(1.0f + e);
}
__device__ __forceinline__ float fast_tanh(float x) {
    float e = __builtin_amdgcn_exp2f(2.88539008f * x);   // exp(2x)
    return __builtin_fmaf(-2.0f, __builtin_amdgcn_rcpf(e + 1.0f), 1.0f);
}

__global__ __launch_bounds__(NT, 2) void lstm_ar_kernel(
    const float* __restrict__ x,
    const float* __restrict__ Wih0, const float* __restrict__ Whh0,
    const float* __restrict__ bih0, const float* __restrict__ bhh0,
    const float* __restrict__ Wih1, const float* __restrict__ Whh1,
    const float* __restrict__ bih1, const float* __restrict__ bhh1,
    const float* __restrict__ Wfc,  const float* __restrict__ bfc,
    float* __restrict__ out)
{
    __shared__ __align__(16) _Float16 A0buf[2][M * A0S];
    __shared__ __align__(16) _Float16 A1buf[2][M * A1S];
    __shared__ __align__(16) _Float16 xAll[XN];            // [elem][t][d] fp16
    __shared__ __align__(16) float    predsS[M * STEPS * D_IN];

    const int tid   = threadIdx.x;
    const int wave  = tid >> 6;
    const int lane  = tid & 63;
    const int n16   = lane & 15;
    const int quad  = lane >> 4;
    const int w4    = wave & 3;        // hidden-column group
    const int whalf = wave >> 2;       // accumulator-row half
    const int rbase = whalf * 2;
    const int m0    = blockIdx.x * M;
    const int m     = n16;             // A-frag row (batch element)
    const int jcol  = 16 * w4 + n16;   // hidden column owned in epilogues

    { _Float16* z = &A0buf[0][0]; for (int i = tid; i < 2 * M * A0S; i += NT) z[i] = (_Float16)0.f; }
    { _Float16* z = &A1buf[0][0]; for (int i = tid; i < 2 * M * A1S; i += NT) z[i] = (_Float16)0.f; }
    for (int j = tid; j < XN / 4; j += NT) {
        const float4v v = *(const float4v*)&x[(size_t)m0 * T_ENC * D_IN + (size_t)j * 4];
        *(half4_t*)&xAll[j * 4] =
            (half4_t){(_Float16)v[0], (_Float16)v[1], (_Float16)v[2], (_Float16)v[3]};
    }

    // ---- weight B-fragments (fp16): B[k][n], n = 16*(w4 + 4*tau) + n16 ----
    half8 B1f[4][4];    // layer1: K=128 = [h0 | h1]
    half8 BW0[4][4];    // encode: [x(4);h0(64);pad] in kt 0..2 (kt3 zero); AR: [Whh0 | Wx]
    float b1v[4], b0v[4], b0arv[4];
    #pragma unroll
    for (int tau = 0; tau < 4; ++tau) {
        const int n = 16 * (w4 + 4 * tau) + n16;
        b1v[tau] = bih1[n] + bhh1[n];
        b0v[tau] = bih0[n] + bhh0[n];
        float wb = 0.f;
        #pragma unroll
        for (int d = 0; d < 4; ++d) wb += Wih0[n * D_IN + d] * bfc[d];
        b0arv[tau] = b0v[tau] + wb;
        #pragma unroll
        for (int kt = 0; kt < 4; ++kt)
            #pragma unroll
            for (int j = 0; j < 8; ++j) {
                const int k = kt * 32 + quad * 8 + j;
                B1f[kt][tau][j] = (_Float16)((k < H) ? Wih1[n * H + k] : Whh1[n * H + (k - H)]);
                float v = 0.f;
                if (k < 4)       v = Wih0[n * D_IN + k];
                else if (k < 68) v = Whh0[n * H + (k - 4)];
                BW0[kt][tau][j] = (_Float16)v;
            }
    }
    // head fragments (w4==0 waves, both whalf)
    half8 Bfc[2];
    float bfcv = 0.f;
    if (w4 == 0) {
        #pragma unroll
        for (int kt = 0; kt < 2; ++kt)
            #pragma unroll
            for (int j = 0; j < 8; ++j) {
                const int k = kt * 32 + quad * 8 + j;
                Bfc[kt][j] = (_Float16)((n16 < 4) ? Wfc[n16 * H + k] : 0.f);
            }
        if (n16 < 4) bfcv = bfc[n16];
    }

    float c0s[2] = {0.f, 0.f};
    float c1s[2] = {0.f, 0.f};

    __syncthreads();   // LDS zero + xAll ready

    // x(0) -> A0buf[1] x-slot (prologue); x(1) -> A0buf[0] (iter-0 input)
    if (w4 == 2 && whalf == 0 && lane < 16) {
        *(half4_t*)&A0buf[1][lane * A0S] = *(const half4_t*)&xAll[(lane * T_ENC + 0) * D_IN];
        *(half4_t*)&A0buf[0][lane * A0S] = *(const half4_t*)&xAll[(lane * T_ENC + 1) * D_IN];
    }
    __syncthreads();

    // ---- prologue: L0 step 0 (all waves dup GEMM, whalf-split epilogue) ----
    {
        half8 a0f[3];
        #pragma unroll
        for (int kt = 0; kt < 3; ++kt)
            a0f[kt] = *(const half8*)&A0buf[1][m * A0S + kt * 32 + quad * 8];
        float4v C0[4];
        #pragma unroll
        for (int tau = 0; tau < 4; ++tau)
            C0[tau] = (float4v){b0v[tau], b0v[tau], b0v[tau], b0v[tau]};
        #pragma unroll
        for (int kt = 0; kt < 3; ++kt)
            #pragma unroll
            for (int tau = 0; tau < 4; ++tau)
                C0[tau] = __builtin_amdgcn_mfma_f32_16x16x32_f16(a0f[kt], BW0[kt][tau], C0[tau], 0, 0, 0);
        #pragma unroll
        for (int rr = 0; rr < 2; ++rr) {
            const int r = rbase + rr;
            const float ig = fast_sigmoid(C0[0][r]);
            const float fg = fast_sigmoid(C0[1][r]);
            const float gg = fast_tanh   (C0[2][r]);
            const float og = fast_sigmoid(C0[3][r]);
            const float c  = fg * c0s[rr] + ig * gg;
            c0s[rr] = c;
            const _Float16 hh = (_Float16)(og * fast_tanh(c));
            const int row = quad * 4 + r;
            A1buf[0][row * A1S + jcol]     = hh;
            A0buf[0][row * A0S + 4 + jcol] = hh;
        }
    }
    __syncthreads();

    // ---- encode: iter t = L1(t) and L0(t+1) on every wave; 1 barrier ----
    for (int t = 0; t < T_ENC; ++t) {
        const int p = t & 1;
        const _Float16* cur0 = &A0buf[p][0];
        const _Float16* cur1 = &A1buf[p][0];
        _Float16* nxt0 = &A0buf[1 - p][0];
        _Float16* nxt1 = &A1buf[1 - p][0];

        half8 a1f[4], a0f[3];
        #pragma unroll
        for (int kt = 0; kt < 4; ++kt)
            a1f[kt] = *(const half8*)&cur1[m * A1S + kt * 32 + quad * 8];
        #pragma unroll
        for (int kt = 0; kt < 3; ++kt)
            a0f[kt] = *(const half8*)&cur0[m * A0S + kt * 32 + quad * 8];

        float4v C1[4], C0[4];
        #pragma unroll
        for (int tau = 0; tau < 4; ++tau) {
            C1[tau] = (float4v){b1v[tau], b1v[tau], b1v[tau], b1v[tau]};
            C0[tau] = (float4v){b0v[tau], b0v[tau], b0v[tau], b0v[tau]};
        }
        #pragma unroll
        for (int kt = 0; kt < 4; ++kt)
            #pragma unroll
            for (int tau = 0; tau < 4; ++tau)
                C1[tau] = __builtin_amdgcn_mfma_f32_16x16x32_f16(a1f[kt], B1f[kt][tau], C1[tau], 0, 0, 0);
        #pragma unroll
        for (int kt = 0; kt < 3; ++kt)
            #pragma unroll
            for (int tau = 0; tau < 4; ++tau)
                C0[tau] = __builtin_amdgcn_mfma_f32_16x16x32_f16(a0f[kt], BW0[kt][tau], C0[tau], 0, 0, 0);

        // epi1: layer1(t) -> h1(t)   (rows rbase..rbase+1 only)
        #pragma unroll
        for (int rr = 0; rr < 2; ++rr) {
            const int r = rbase + rr;
            const float ig = fast_sigmoid(C1[0][r]);
            const float fg = fast_sigmoid(C1[1][r]);
            const float gg = fast_tanh   (C1[2][r]);
            const float og = fast_sigmoid(C1[3][r]);
            const float c  = fg * c1s[rr] + ig * gg;
            c1s[rr] = c;
            nxt1[(quad * 4 + r) * A1S + 64 + jcol] = (_Float16)(og * fast_tanh(c));
        }
        // epi0: layer0(t+1) -> h0(t+1)
        #pragma unroll
        for (int rr = 0; rr < 2; ++rr) {
            const int r = rbase + rr;
            const float ig = fast_sigmoid(C0[0][r]);
            const float fg = fast_sigmoid(C0[1][r]);
            const float gg = fast_tanh   (C0[2][r]);
            const float og = fast_sigmoid(C0[3][r]);
            const float c  = fg * c0s[rr] + ig * gg;
            c0s[rr] = c;
            const _Float16 hh = (_Float16)(og * fast_tanh(c));
            const int row = quad * 4 + r;
            nxt1[row * A1S + jcol]     = hh;
            nxt0[row * A0S + 4 + jcol] = hh;
        }
        if (w4 == 2 && whalf == 0 && lane < 16) {   // x(t+2) -> nxt0 x-slot
            int tn = t + 2; if (tn > T_ENC - 1) tn = T_ENC - 1;
            *(half4_t*)&nxt0[lane * A0S] = *(const half4_t*)&xAll[(lane * T_ENC + tn) * D_IN];
        }
        __syncthreads();
    }

    // ---- AR prep: overwrite BW0 in place -> [Whh0 | Wx = Wih0@Wfc] ----
    #pragma unroll
    for (int tau = 0; tau < 4; ++tau) {
        const int n = 16 * (w4 + 4 * tau) + n16;
        #pragma unroll
        for (int kt = 0; kt < 4; ++kt)
            #pragma unroll
            for (int j = 0; j < 8; ++j) {
                const int k = kt * 32 + quad * 8 + j;
                float v;
                if (k < H) v = Whh0[n * H + k];
                else {
                    const int c = k - H;
                    v = Wih0[n * D_IN + 0] * Wfc[0 * H + c] + Wih0[n * D_IN + 1] * Wfc[1 * H + c]
                      + Wih0[n * D_IN + 2] * Wfc[2 * H + c] + Wih0[n * D_IN + 3] * Wfc[3 * H + c];
                }
                BW0[kt][tau][j] = (_Float16)v;
            }
    }

    // ---- AR: phase1 = full L1 over cur=[h0(s)|h1(s-1)] -> h1(s); barrier;
    //          phase2 = L0ar over [h0(s)|h1(s)] -> h0(s+1), head on w4==0; barrier ----
    for (int s = 0; s < STEPS; ++s) {
        const int q = s & 1;
        const _Float16* cur = &A1buf[q][0];
        _Float16* nxt = &A1buf[1 - q][0];

        half8 a1f[4];
        #pragma unroll
        for (int kt = 0; kt < 4; ++kt)
            a1f[kt] = *(const half8*)&cur[m * A1S + kt * 32 + quad * 8];
        float4v C1[4];
        #pragma unroll
        for (int tau = 0; tau < 4; ++tau)
            C1[tau] = (float4v){b1v[tau], b1v[tau], b1v[tau], b1v[tau]};
        #pragma unroll
        for (int kt = 0; kt < 4; ++kt)
            #pragma unroll
            for (int tau = 0; tau < 4; ++tau)
                C1[tau] = __builtin_amdgcn_mfma_f32_16x16x32_f16(a1f[kt], B1f[kt][tau], C1[tau], 0, 0, 0);
        #pragma unroll
        for (int rr = 0; rr < 2; ++rr) {
            const int r = rbase + rr;
            const float ig = fast_sigmoid(C1[0][r]);
            const float fg = fast_sigmoid(C1[1][r]);
            const float gg = fast_tanh   (C1[2][r]);
            const float og = fast_sigmoid(C1[3][r]);
            const float c  = fg * c1s[rr] + ig * gg;
            c1s[rr] = c;
            nxt[(quad * 4 + r) * A1S + 64 + jcol] = (_Float16)(og * fast_tanh(c));
        }
        __syncthreads();   // h1(s) visible

        half8 aA[4];
        #pragma unroll
        for (int kt = 0; kt < 2; ++kt)
            aA[kt] = *(const half8*)&cur[m * A1S + kt * 32 + quad * 8];            // h0(s)
        #pragma unroll
        for (int kt = 0; kt < 2; ++kt)
            aA[2 + kt] = *(const half8*)&nxt[m * A1S + 64 + kt * 32 + quad * 8];   // h1(s)
        float4v C0[4];
        #pragma unroll
        for (int tau = 0; tau < 4; ++tau)
            C0[tau] = (float4v){b0arv[tau], b0arv[tau], b0arv[tau], b0arv[tau]};
        #pragma unroll
        for (int kt = 0; kt < 4; ++kt)
            #pragma unroll
            for (int tau = 0; tau < 4; ++tau)
                C0[tau] = __builtin_amdgcn_mfma_f32_16x16x32_f16(aA[kt], BW0[kt][tau], C0[tau], 0, 0, 0);

        if (w4 == 0) {   // head: pred(s) = Wfc·h1(s)+bfc (output only, off critical path)
            float4v Cp = (float4v){bfcv, bfcv, bfcv, bfcv};
            Cp = __builtin_amdgcn_mfma_f32_16x16x32_f16(aA[2], Bfc[0], Cp, 0, 0, 0);
            Cp = __builtin_amdgcn_mfma_f32_16x16x32_f16(aA[3], Bfc[1], Cp, 0, 0, 0);
            if (n16 < 4) {
                #pragma unroll
                for (int rr = 0; rr < 2; ++rr) {
                    const int r = rbase + rr;
                    predsS[(quad * 4 + r) * (STEPS * D_IN) + s * D_IN + n16] = Cp[r];
                }
            }
        }

        #pragma unroll
        for (int rr = 0; rr < 2; ++rr) {
            const int r = rbase + rr;
            const float ig = fast_sigmoid(C0[0][r]);
            const float fg = fast_sigmoid(C0[1][r]);
            const float gg = fast_tanh   (C0[2][r]);
            const float og = fast_sigmoid(C0[3][r]);
            const float c  = fg * c0s[rr] + ig * gg;
            c0s[rr] = c;
            nxt[(quad * 4 + r) * A1S + jcol] = (_Float16)(og * fast_tanh(c));
        }
        __syncthreads();   // h0(s+1) visible
    }

    // ---- bulk store preds ----
    for (int j = tid; j < M * STEPS; j += NT) {
        const int elem = j / STEPS, r = j - elem * STEPS;
        ((float4v*)out)[(size_t)(m0 + elem) * STEPS + r] = ((const float4v*)predsS)[j];
    }
}

extern "C" void kernel_launch(void* const* d_in, const int* in_sizes, int n_in,
                              void* d_out, int out_size, void* d_ws, size_t ws_size,
                              hipStream_t stream) {
    const float* x    = (const float*)d_in[0];
    const float* Wih0 = (const float*)d_in[1];
    const float* Whh0 = (const float*)d_in[2];
    const float* bih0 = (const float*)d_in[3];
    const float* bhh0 = (const float*)d_in[4];
    const float* Wih1 = (const float*)d_in[5];
    const float* Whh1 = (const float*)d_in[6];
    const float* bih1 = (const float*)d_in[7];
    const float* bhh1 = (const float*)d_in[8];
    const float* Wfc  = (const float*)d_in[9];
    const float* bfc  = (const float*)d_in[10];
    float* out = (float*)d_out;

    dim3 grid(4096 / M);   // 256 blocks, one per CU
    dim3 block(NT);        // 8 waves = 2 per SIMD
    lstm_ar_kernel<<<grid, block, 0, stream>>>(
        x, Wih0, Whh0, bih0, bhh0, Wih1, Whh1, bih1, bhh1, Wfc, bfc, out);
}